// Round 10
// baseline (229.548 us; speedup 1.0000x reference)
//
#include <hip/hip_runtime.h>

#define B_DIM 64
#define C_DIM 768
#define HID_DIM 768
#define PLANE 576          // 24*24 floats per channel plane
#define PLANE4 144         // float4 per plane
#define KC 48              // k-chunk for FC kernels
#define OT 64              // o-tile for FC kernels
#define FC_BLOCKS ((HID_DIM / OT) * (HID_DIM / KC))   // 12*16 = 192

__device__ __forceinline__ float hatcdf(float t) {
    // 0 for t<=-1, 0.5(t+1)^2 for -1<t<=0, 1-0.5(1-t)^2 for 0<t<=1, 1 for t>1
    float u = fminf(fmaxf(t, -1.f), 1.f);
    float a = u + 1.f;
    float b = 1.f - u;
    return (t <= 0.f) ? 0.5f * a * a : 1.f - 0.5f * b * b;
}

// K1: feat[b,c] = S_b * sum_{h,w} X[b,c,h,w] * wy[h] * wx[w]
// Weight support is a contiguous rectangle: wx[c] != 0 only for
// c in (x0-1, x1+1), wy[h] != 0 only for h in (y0-1, y1+1). Fetch only
// rows [hlo,hhi] and float4 column groups [c4lo,c4hi] (~25-40% of bytes).
// 2048 blocks x 256 threads; block bx owns b = bx>>5, channels (bx&31)*24..+23,
// each wave 6 planes. Lane = (row8, col8): 8 rows x 8 col4 slots.
// Blocks 0..95 zero x1raw/x2raw; block 96 zeroes the fc2 done-counter.
__global__ __launch_bounds__(256) void pool_kernel(
    const float* __restrict__ X, const float* __restrict__ box,
    float* __restrict__ feat, float* __restrict__ zbuf,
    unsigned int* __restrict__ counter)
{
    const int t = threadIdx.x;
    const int bx = blockIdx.x;
    if (bx < 96) {  // 96*256 float4 = 98304 floats = x1raw..x2raw
        reinterpret_cast<float4*>(zbuf)[bx * 256 + t] = make_float4(0.f, 0.f, 0.f, 0.f);
    } else if (bx == 96 && t == 0) {
        *counter = 0u;
    }
    const int b = bx >> 5;

    __shared__ float wx[24], wy[24];
    __shared__ float sscale;
    __shared__ int bnd[4];   // hlo, hhi, c4lo, c4hi
    if (t < 51) {
        const float x0 = box[b * 4 + 0] * 24.f;
        const float y0 = box[b * 4 + 1] * 24.f;
        const float x1 = box[b * 4 + 2] * 24.f;
        const float y1 = box[b * 4 + 3] * 24.f;
        if (t < 24) {
            wx[t] = hatcdf(x1 - (float)t) - hatcdf(x0 - (float)t);
        } else if (t < 48) {
            const int h = t - 24;
            wy[h] = hatcdf(y1 - (float)h) - hatcdf(y0 - (float)h);
        } else if (t == 48) {
            const float bw = (x1 - x0) * 0.25f;
            const float bh = (y1 - y0) * 0.25f;
            const float area = bw * bh;
            sscale = (area > 0.f) ? 1.f / (16.f * fmaxf(area, 1e-12f)) : 0.f;
        } else if (t == 49) {
            bnd[0] = max(0, (int)y0 - 1);
            bnd[1] = min(23, (int)y1 + 2);
        } else {  // t == 50
            const int wlo = max(0, (int)x0 - 1);
            const int whi = min(23, (int)x1 + 2);
            bnd[2] = wlo >> 2;
            bnd[3] = whi >> 2;
        }
    }
    __syncthreads();

    const int hlo = bnd[0], hhi = bnd[1];
    const int c4lo = bnd[2], c4hi = bnd[3];

    const int wave = t >> 6;
    const int lane = t & 63;
    const int c0 = (bx & 31) * 24 + wave * 6;
    const float4* __restrict__ P =
        reinterpret_cast<const float4*>(X + ((size_t)b * C_DIM + c0) * PLANE);

    const int r8 = lane >> 3;          // 0..7 : row slot
    const int c4 = c4lo + (lane & 7);  // col4 slot (may exceed c4hi)

    float acc[6];
    #pragma unroll
    for (int p = 0; p < 6; ++p) acc[p] = 0.f;

    if (c4 <= c4hi) {
        const float wx0 = wx[c4 * 4 + 0];
        const float wx1 = wx[c4 * 4 + 1];
        const float wx2 = wx[c4 * 4 + 2];
        const float wx3 = wx[c4 * 4 + 3];
        for (int r = hlo + r8; r <= hhi; r += 8) {
            const float wyr = wy[r];
            const int off = r * 6 + c4;
            #pragma unroll
            for (int p = 0; p < 6; ++p) {
                const float4 v = P[p * PLANE4 + off];
                acc[p] += wyr * (v.x * wx0 + v.y * wx1 + v.z * wx2 + v.w * wx3);
            }
        }
    }

    #pragma unroll
    for (int p = 0; p < 6; ++p) {
        float a = acc[p];
        #pragma unroll
        for (int off = 32; off; off >>= 1) a += __shfl_down(a, off);
        if (lane == 0) feat[(size_t)b * C_DIM + c0 + p] = a * sscale;
    }
}

// shared FC tile body: As/Ws staging + 4x4 register-blocked partial GEMM.
template <bool RELU_IN>
__device__ __forceinline__ void fc_body(
    const float* __restrict__ A, const float* __restrict__ bias,
    const float* __restrict__ Wm, float* __restrict__ Out,
    float (*As)[68], float (*Ws)[68], int t, int ot, int kc)
{
    for (int j = t; j < B_DIM * (KC / 4); j += 256) {
        const int bb = j / (KC / 4);
        const int k4 = (j % (KC / 4)) * 4;
        float4 v = *reinterpret_cast<const float4*>(A + (size_t)bb * HID_DIM + kc + k4);
        if constexpr (RELU_IN) {
            const float4 bv = *reinterpret_cast<const float4*>(bias + kc + k4);
            v.x = fmaxf(v.x + bv.x, 0.f);
            v.y = fmaxf(v.y + bv.y, 0.f);
            v.z = fmaxf(v.z + bv.z, 0.f);
            v.w = fmaxf(v.w + bv.w, 0.f);
        }
        As[k4 + 0][bb] = v.x;
        As[k4 + 1][bb] = v.y;
        As[k4 + 2][bb] = v.z;
        As[k4 + 3][bb] = v.w;
    }
    for (int j = t; j < KC * (OT / 4); j += 256) {
        const int k = j / (OT / 4);
        const int oo = (j % (OT / 4)) * 4;
        const float4 v = *reinterpret_cast<const float4*>(Wm + (size_t)(kc + k) * HID_DIM + ot + oo);
        *reinterpret_cast<float4*>(&Ws[k][oo]) = v;
    }
    __syncthreads();

    const int b0 = (t >> 4) * 4;
    const int o0 = (t & 15) * 4;
    float acc[4][4] = {};
    #pragma unroll 6
    for (int k = 0; k < KC; ++k) {
        const float4 a = *reinterpret_cast<const float4*>(&As[k][b0]);
        const float4 w = *reinterpret_cast<const float4*>(&Ws[k][o0]);
        acc[0][0] += a.x * w.x; acc[0][1] += a.x * w.y; acc[0][2] += a.x * w.z; acc[0][3] += a.x * w.w;
        acc[1][0] += a.y * w.x; acc[1][1] += a.y * w.y; acc[1][2] += a.y * w.z; acc[1][3] += a.y * w.w;
        acc[2][0] += a.z * w.x; acc[2][1] += a.z * w.y; acc[2][2] += a.z * w.z; acc[2][3] += a.z * w.w;
        acc[3][0] += a.w * w.x; acc[3][1] += a.w * w.y; acc[3][2] += a.w * w.z; acc[3][3] += a.w * w.w;
    }
    #pragma unroll
    for (int i = 0; i < 4; ++i)
        #pragma unroll
        for (int j = 0; j < 4; ++j)
            atomicAdd(&Out[(size_t)(b0 + i) * HID_DIM + ot + o0 + j], acc[i][j]);
}

// K2: fc1 (no input relu/bias)
__global__ __launch_bounds__(256) void fc1_kernel(
    const float* __restrict__ A, const float* __restrict__ bias,
    const float* __restrict__ Wm, float* __restrict__ Out)
{
    __shared__ float As[KC][68];
    __shared__ float Ws[KC][68];
    fc_body<false>(A, bias, Wm, Out, As, Ws, threadIdx.x,
                   blockIdx.x * OT, blockIdx.y * KC);
}

// K3: fc2 (fused relu(x1+b1) on load) + head done by the LAST block to finish.
// Each block: __threadfence, atomicAdd(counter); the block observing
// counter == FC_BLOCKS-1 knows all x2raw atomics are device-visible and
// computes out[b] = b3 + sum_o relu(x2raw[b,o]+b2[o])*w3[o].
__global__ __launch_bounds__(256) void fc2_head_kernel(
    const float* __restrict__ A, const float* __restrict__ bias,
    const float* __restrict__ Wm, float* __restrict__ Out,
    const float* __restrict__ b2, const float* __restrict__ w3,
    const float* __restrict__ b3, float* __restrict__ out,
    unsigned int* __restrict__ counter)
{
    __shared__ float As[KC][68];
    __shared__ float Ws[KC][68];
    const int t = threadIdx.x;
    fc_body<true>(A, bias, Wm, Out, As, Ws, t,
                  blockIdx.x * OT, blockIdx.y * KC);

    __threadfence();
    __shared__ unsigned int done;
    __syncthreads();
    if (t == 0) done = atomicAdd(counter, 1u);
    __syncthreads();
    if (done != FC_BLOCKS - 1) return;
    __threadfence();   // acquire: all blocks' x2raw atomics now visible

    // head: thread t -> b = t>>2, o-slice q = t&3 (192 o's each)
    const int b = t >> 2;
    const int q = t & 3;
    float acc = 0.f;
    for (int o = q; o < HID_DIM; o += 4)
        acc += fmaxf(Out[(size_t)b * HID_DIM + o] + b2[o], 0.f) * w3[o];
    acc += __shfl_xor(acc, 1);
    acc += __shfl_xor(acc, 2);
    if (q == 0) out[b] = acc + b3[0];
}

extern "C" void kernel_launch(void* const* d_in, const int* in_sizes, int n_in,
                              void* d_out, int out_size, void* d_ws, size_t ws_size,
                              hipStream_t stream) {
    const float* X   = (const float*)d_in[0];
    const float* box = (const float*)d_in[1];
    const float* w1  = (const float*)d_in[2];
    const float* b1  = (const float*)d_in[3];
    const float* w2  = (const float*)d_in[4];
    const float* b2  = (const float*)d_in[5];
    const float* w3  = (const float*)d_in[6];
    const float* b3  = (const float*)d_in[7];
    float* out = (float*)d_out;

    float* feat  = (float*)d_ws;                    // 64*768
    float* x1raw = feat + B_DIM * HID_DIM;          // 64*768 (zeroed by K1)
    float* x2raw = x1raw + B_DIM * HID_DIM;         // 64*768 (zeroed by K1)
    unsigned int* counter = (unsigned int*)(x2raw + B_DIM * HID_DIM);  // zeroed by K1

    pool_kernel<<<2048, 256, 0, stream>>>(X, box, feat, x1raw, counter);
    fc1_kernel<<<dim3(HID_DIM / OT, HID_DIM / KC), 256, 0, stream>>>(feat, b1, w1, x1raw);
    fc2_head_kernel<<<dim3(HID_DIM / OT, HID_DIM / KC), 256, 0, stream>>>(
        x1raw, b1, w2, x2raw, b2, w3, b3, out, counter);
}